// Round 16
// baseline (1408.738 us; speedup 1.0000x reference)
//
#include <hip/hip_runtime.h>
#include <hip/hip_bf16.h>
#include <stdint.h>

// ---------------------------------------------------------------------------
// SpMiddle conv stack — fp16 MFMA implicit-GEMM, v6.
// = v4's proven structure (16x16x32, KH-merged staging, 64-wide w-tiles,
//   256 thr, XOR swizzle with 2-way-free A reads) with two changes:
//   (1) no N-split: each wave owns 16 UNIQUE rows x full COUT (nf=COUT/16)
//       -> A-read duplication 2x -> 1x, MFMA per LDS byte doubled
//       (v4 measured LDS-read-bound: MfmaUtil 26%).
//   (2) bijective XCD swizzle on a 1D grid (nwg%8==0 for every layer) so
//       each XCD's L2 serves a contiguous od/oh slab (FETCH was 1.5x input).
// ---------------------------------------------------------------------------

typedef _Float16 h8 __attribute__((ext_vector_type(8)));
typedef float f4 __attribute__((ext_vector_type(4)));

#define HCONST 128
#define WCONST 128

// ---- scatter: last-write-wins via owner = atomicMax(point index) ----------
__global__ void scatter_owner_kernel(const int* __restrict__ coords,
                                     int* __restrict__ owner,
                                     unsigned char* __restrict__ mask0, int N) {
    int n = blockIdx.x * blockDim.x + threadIdx.x;
    if (n >= N) return;
    int z = coords[n * 4 + 1];
    int y = coords[n * 4 + 2];
    int x = coords[n * 4 + 3];
    int pos = (z * HCONST + y) * WCONST + x;
    atomicMax(&owner[pos], n);
    mask0[pos] = 1;
}

// grid has 32 channels (ci 16..31 stay zero from memset); fp16
__global__ void scatter_write_kernel(const float* __restrict__ feats,
                                     const int* __restrict__ coords,
                                     const int* __restrict__ owner,
                                     _Float16* __restrict__ grid, int N) {
    int n = blockIdx.x * blockDim.x + threadIdx.x;
    if (n >= N) return;
    int z = coords[n * 4 + 1];
    int y = coords[n * 4 + 2];
    int x = coords[n * 4 + 3];
    int pos = (z * HCONST + y) * WCONST + x;
    if (owner[pos] != n) return;  // last write wins
    _Float16* d = grid + (size_t)pos * 32;
#pragma unroll
    for (int c = 0; c < 16; ++c) d[c] = (_Float16)feats[(size_t)n * 16 + c];
}

// ---- occupancy mask: OR over conv window -----------------------------------
template <int KD, int KHW, int SD, int PD, int PHW>
__global__ void occupancy_kernel(const unsigned char* __restrict__ min_,
                                 unsigned char* __restrict__ mout,
                                 int Din, int Dout) {
    int idx = blockIdx.x * blockDim.x + threadIdx.x;
    int total = Dout * HCONST * WCONST;
    if (idx >= total) return;
    int ow = idx % WCONST;
    int oh = (idx / WCONST) % HCONST;
    int od = idx / (WCONST * HCONST);
    unsigned char r = 0;
    for (int kd = 0; kd < KD; ++kd) {
        int d = od * SD - PD + kd;
        if (d < 0 || d >= Din) continue;
        for (int kh = 0; kh < KHW; ++kh) {
            int h = oh - PHW + kh;
            if ((unsigned)h >= (unsigned)HCONST) continue;
            for (int kw = 0; kw < KHW; ++kw) {
                int w = ow - PHW + kw;
                if ((unsigned)w >= (unsigned)WCONST) continue;
                r |= min_[(d * HCONST + h) * WCONST + w];
            }
        }
    }
    mout[idx] = r ? 1 : 0;
}

// ---- weight prep: fp32 [k][ci][co] -> fp16 [k][ks][lq][co][8] --------------
__global__ void prep_w_kernel(const float* __restrict__ src, _Float16* __restrict__ dst,
                              int K3, int CIN, int CINP, int COUT) {
    int idx = blockIdx.x * blockDim.x + threadIdx.x;
    int total = K3 * CINP * COUT;           // CINP = KSP*4*8
    if (idx >= total) return;
    int j  = idx & 7;
    int t  = idx >> 3;
    int co = t % COUT; t /= COUT;
    int lq = t & 3;    t >>= 2;
    int KSP = CINP / 32;
    int ks = t % KSP;
    int k  = t / KSP;
    int ci = ks * 32 + lq * 8 + j;
    float v = (ci < CIN) ? src[((size_t)k * CIN + ci) * COUT + co] : 0.f;
    dst[idx] = (_Float16)v;
}

// ---- conv + BN + ReLU + mask, fp16 MFMA implicit GEMM ----------------------
// Block = one (w-tile, oh, od) decoded from a XCD-swizzled 1D grid.
// M = 64 w-positions, N = COUT. 4 waves, each owning 16 UNIQUE rows
// (rows wave*16..+16) x full COUT (NFRAG = COUT/16 n-frags). No A dup.
// Per kd: stage KH rows x 66 w into XOR-swizzled LDS (one barrier pair),
// then KH*KW*KS phases: 1 A-read feeds NFRAG MFMAs.
template <int CIN, int COUT, int KD, int KHW, int SD, int PD, int PHW, bool OUT_F32>
__global__ __launch_bounds__(256) void conv_mfma_kernel(
    const _Float16* __restrict__ X, const _Float16* __restrict__ Wt,
    const float* __restrict__ scale, const float* __restrict__ bias,
    const unsigned char* __restrict__ mask, void* __restrict__ outv,
    int Din) {
    constexpr int KW = KHW, KH = KHW;
    constexpr int KS = CIN / 32;            // 32-wide k-slices per kw
    constexpr int NFRAG = COUT / 16;        // full COUT per wave
    constexpr int PWOFF = (KHW == 3) ? 1 : 0;
    constexpr int WINW = 64 + 2 * PWOFF;    // staged w extent per row (66|64)
    constexpr int CINB = CIN * 2;           // row bytes (pow2 -> XOR swizzle)
    constexpr int CPR = CIN / 8;            // 16B chunks per row
    constexpr int CHUNKS = KH * WINW * CPR; // chunks staged per kd
    constexpr int NIT = (CHUNKS + 255) / 256;

    __shared__ char lds[KH * WINW * CINB];

    const int tid = threadIdx.x;
    const int lane = tid & 63, wave = tid >> 6;
    const int lm = lane & 15, lq = lane >> 4;
    // bijective XCD swizzle (gridDim.x % 8 == 0 for every layer)
    const int cpx = gridDim.x >> 3;
    const int bid = blockIdx.x;
    const int d   = (bid & 7) * cpx + (bid >> 3);
    const int wbase = (d & 1) * 64;
    const int oh = (d >> 1) & 127;
    const int od = d >> 8;

    f4 acc[NFRAG];
#pragma unroll
    for (int nf = 0; nf < NFRAG; ++nf) acc[nf] = (f4){0.f, 0.f, 0.f, 0.f};

    for (int kd = 0; kd < KD; ++kd) {
        int din = od * SD - PD + kd;
        if (din < 0 || din >= Din) continue;          // block-uniform
        __syncthreads();                              // protect prev LDS reads
        // ---- stage KH rows for this kd (zero-fill OOB rows/cols) ----
        const _Float16* sbase = X + (size_t)din * 128 * 128 * CIN;
#pragma unroll
        for (int it = 0; it < NIT; ++it) {
            int c = tid + it * 256;
            if (c < CHUNKS) {
                int r  = c / CPR;           // staged row index (kh*WINW + lw)
                int cq = c % CPR;
                int khr = r / WINW;
                int lw  = r % WINW;
                int hin = oh - PHW + khr;
                int w   = wbase + lw - PWOFF;
                uint4 v = {0u, 0u, 0u, 0u};
                if ((unsigned)hin < 128u && (unsigned)w < 128u)
                    v = *(const uint4*)(sbase + ((size_t)hin * 128 + w) * CIN + cq * 8);
                int byte = r * CINB + ((cq * 16) ^ ((r & (CPR - 1)) << 4));
                *(uint4*)(lds + byte) = v;
            }
        }
        __syncthreads();
        // ---- compute: KH x KW x KS phases, 1 A-read -> NFRAG MFMAs ----
#pragma unroll
        for (int kh = 0; kh < KH; ++kh) {
            const _Float16* wbaseW = Wt + (size_t)(kd * KH + kh) * KW * KS * 4 * COUT * 8;
#pragma unroll
            for (int kw = 0; kw < KW; ++kw) {
                h8 Bf[KS][NFRAG];
#pragma unroll
                for (int ks = 0; ks < KS; ++ks)
#pragma unroll
                    for (int nf = 0; nf < NFRAG; ++nf) {
                        int co = nf * 16 + lm;
                        Bf[ks][nf] =
                            *(const h8*)(wbaseW + (((size_t)(kw * KS + ks) * 4 + lq) * COUT + co) * 8);
                    }
#pragma unroll
                for (int ks = 0; ks < KS; ++ks) {
                    int lw = wave * 16 + lm + kw;
                    int r = kh * WINW + lw;
                    int byte = r * CINB + ((ks * 64 + lq * 16) ^ ((r & (CPR - 1)) << 4));
                    h8 Af = *(const h8*)(lds + byte);
#pragma unroll
                    for (int nf = 0; nf < NFRAG; ++nf)
                        acc[nf] = __builtin_amdgcn_mfma_f32_16x16x32_f16(
                            Af, Bf[ks][nf], acc[nf], 0, 0, 0);
                }
            }
        }
    }

    // epilogue: y = max(acc*s + b, 0) * mask; C layout col=lane&15(n), row=lq*4+r(m)
    const unsigned char* mrow = mask + ((size_t)od * 128 + oh) * 128 + wbase;
    size_t obase = (((size_t)od * 128 + oh) * 128 + wbase) * COUT;
#pragma unroll
    for (int nf = 0; nf < NFRAG; ++nf) {
        int co = nf * 16 + lm;
        float s = scale[co];
        float b = bias[co];
        int w0 = wave * 16 + lq * 4;
#pragma unroll
        for (int r = 0; r < 4; ++r) {
            float y = fmaxf(acc[nf][r] * s + b, 0.f);
            y = mrow[w0 + r] ? y : 0.f;
            if (OUT_F32)
                ((float*)outv)[obase + (size_t)(w0 + r) * COUT + co] = y;
            else
                ((_Float16*)outv)[obase + (size_t)(w0 + r) * COUT + co] = (_Float16)y;
        }
    }
}

// ---------------------------------------------------------------------------
extern "C" void kernel_launch(void* const* d_in, const int* in_sizes, int n_in,
                              void* d_out, int out_size, void* d_ws, size_t ws_size,
                              hipStream_t stream) {
    const float* feats  = (const float*)d_in[0];
    const int*   coords = (const int*)d_in[1];
    const float* W_[11]; const float* S_[11]; const float* B_[11];
    for (int i = 0; i < 11; ++i) {
        W_[i] = (const float*)d_in[2 + 3 * i];
        S_[i] = (const float*)d_in[3 + 3 * i];
        B_[i] = (const float*)d_in[4 + 3 * i];
    }
    const int N = in_sizes[0] / 16;

    char* ws = (char*)d_ws;
    size_t off = 0;
    auto alloc = [&](size_t bytes) {
        void* p = ws + off;
        off = (off + bytes + 255) & ~(size_t)255;
        return p;
    };
    // fp16 ping-pong activation buffers (max layer: 344064*64 halves = 44 MB)
    const size_t BUF_BYTES = (size_t)22020096 * 2;
    _Float16* buf0 = (_Float16*)alloc(BUF_BYTES);
    _Float16* buf1 = (_Float16*)alloc(BUF_BYTES);
    unsigned char* m0 = (unsigned char*)alloc(671744);
    unsigned char* m1 = (unsigned char*)alloc(344064);
    unsigned char* m2 = (unsigned char*)alloc(163840);
    unsigned char* m3 = (unsigned char*)alloc(65536);
    int* owner = (int*)alloc((size_t)671744 * 4);
    // repacked fp16 weights (element counts: K3 * COUT * CINP)
    static const int WT_SZ[11] = {27*32*32, 27*32*32, 27*64*32,
                                  27*64*64, 27*64*64, 27*64*64, 27*64*64,
                                  27*64*64, 27*64*64, 27*64*64, 3*64*64};
    _Float16* Wt[11];
    for (int i = 0; i < 11; ++i) Wt[i] = (_Float16*)alloc((size_t)WT_SZ[i] * 2);
    (void)ws_size; (void)n_in; (void)out_size;

    _Float16* grid0 = buf1;  // (41,128,128,32) fp16 aliased into buf1
    const size_t GRID_BYTES = (size_t)671744 * 32 * 2;

    hipMemsetAsync(grid0, 0, GRID_BYTES, stream);
    hipMemsetAsync(m0, 0, 671744, stream);
    hipMemsetAsync(owner, 0xFF, (size_t)671744 * 4, stream);

    scatter_owner_kernel<<<(N + 255) / 256, 256, 0, stream>>>(coords, owner, m0, N);
    scatter_write_kernel<<<(N + 255) / 256, 256, 0, stream>>>(feats, coords, owner, grid0, N);

    occupancy_kernel<3, 3, 2, 1, 1><<<(21 * 128 * 128 + 255) / 256, 256, 0, stream>>>(m0, m1, 41, 21);
    occupancy_kernel<3, 3, 2, 0, 1><<<(10 * 128 * 128 + 255) / 256, 256, 0, stream>>>(m1, m2, 21, 10);
    occupancy_kernel<3, 1, 2, 0, 0><<<(4 * 128 * 128 + 255) / 256, 256, 0, stream>>>(m2, m3, 10, 4);

    // weight prep (w0 padded ci 16->32); layout [k][ks][lq][co][8]
    {
        static const int K3[11]   = {27,27,27,27,27,27,27,27,27,27,3};
        static const int CI[11]   = {16,32,32,64,64,64,64,64,64,64,64};
        static const int CIP[11]  = {32,32,32,64,64,64,64,64,64,64,64};
        static const int CO[11]   = {32,32,64,64,64,64,64,64,64,64,64};
        for (int i = 0; i < 11; ++i) {
            int total = K3[i] * CO[i] * CIP[i];
            prep_w_kernel<<<(total + 255) / 256, 256, 0, stream>>>(W_[i], Wt[i], K3[i], CI[i], CIP[i], CO[i]);
        }
    }

    // conv stack: 1D grid = 2*128*Dout (divisible by 8), XCD-swizzled in-kernel
    conv_mfma_kernel<32, 32, 3, 3, 1, 1, 1, false><<<2 * 128 * 41, 256, 0, stream>>>(
        grid0, Wt[0], S_[0], B_[0], m0, buf0, 41);
    conv_mfma_kernel<32, 32, 3, 3, 1, 1, 1, false><<<2 * 128 * 41, 256, 0, stream>>>(
        buf0, Wt[1], S_[1], B_[1], m0, buf1, 41);
    conv_mfma_kernel<32, 64, 3, 3, 2, 1, 1, false><<<2 * 128 * 21, 256, 0, stream>>>(
        buf1, Wt[2], S_[2], B_[2], m1, buf0, 41);
    conv_mfma_kernel<64, 64, 3, 3, 1, 1, 1, false><<<2 * 128 * 21, 256, 0, stream>>>(
        buf0, Wt[3], S_[3], B_[3], m1, buf1, 21);
    conv_mfma_kernel<64, 64, 3, 3, 1, 1, 1, false><<<2 * 128 * 21, 256, 0, stream>>>(
        buf1, Wt[4], S_[4], B_[4], m1, buf0, 21);
    conv_mfma_kernel<64, 64, 3, 3, 1, 1, 1, false><<<2 * 128 * 21, 256, 0, stream>>>(
        buf0, Wt[5], S_[5], B_[5], m1, buf1, 21);
    conv_mfma_kernel<64, 64, 3, 3, 2, 0, 1, false><<<2 * 128 * 10, 256, 0, stream>>>(
        buf1, Wt[6], S_[6], B_[6], m2, buf0, 21);
    conv_mfma_kernel<64, 64, 3, 3, 1, 1, 1, false><<<2 * 128 * 10, 256, 0, stream>>>(
        buf0, Wt[7], S_[7], B_[7], m2, buf1, 10);
    conv_mfma_kernel<64, 64, 3, 3, 1, 1, 1, false><<<2 * 128 * 10, 256, 0, stream>>>(
        buf1, Wt[8], S_[8], B_[8], m2, buf0, 10);
    conv_mfma_kernel<64, 64, 3, 3, 1, 1, 1, false><<<2 * 128 * 10, 256, 0, stream>>>(
        buf0, Wt[9], S_[9], B_[9], m2, buf1, 10);
    conv_mfma_kernel<64, 64, 3, 1, 2, 0, 0, true><<<2 * 128 * 4, 256, 0, stream>>>(
        buf1, Wt[10], S_[10], B_[10], m3, (float*)d_out, 10);
}